// Round 15
// baseline (293.835 us; speedup 1.0000x reference)
//
#include <hip/hip_runtime.h>
#include <hip/hip_fp16.h>

#define N_NODES 100000
#define N_EDGES 1600000
#define D 128
#define NBKT 391        // ceil(100000/256) buckets of 256 dst nodes
#define BKT_CAP 5120    // mean bucket size 4096, sigma~64 -> 16-sigma margin
#define NB_GEMM 782     // ceil(100000/128) 128-row MFMA blocks
#define NB_BINA 782     // ceil((1600000/4)/512) edge-quad blocks
#define QCAP 1536       // quarter-bucket LDS edge-list capacity (mean 1024, 16-sigma)

typedef _Float16 f16x8 __attribute__((ext_vector_type(8)));
typedef float f32x4 __attribute__((ext_vector_type(4)));

// XOR-swizzle for 256B-row-stride LDS tiles (see R7).
#define SWZ(b) ((b) ^ ((((b) >> 8) & 7) << 4))

// ==================== mega: MFMA gemm1 blocks || binA'(bin + degree) blocks ====================
// gemm: q = fp16(feature @ W1), q[node][128] (R9-validated).
// binA': bucket records (src<<8|dst_local) + global per-node degree histogram cnt[].

__global__ __launch_bounds__(512) void mega_kernel(const float* __restrict__ x,
                                                   const float* __restrict__ W,
                                                   _Float16* __restrict__ q,
                                                   const int* __restrict__ src,
                                                   const int* __restrict__ dst,
                                                   int* __restrict__ cnt,
                                                   int* __restrict__ gcnt,
                                                   int* __restrict__ staged) {
    __shared__ __align__(16) char smem[32768];
    const int tid = threadIdx.x;
    const int bid = blockIdx.x;

    if (bid < NB_GEMM) {
        // ---- MFMA gemm1 path (R9-validated: absmax 9.8e-4) ----
        const int lane = tid & 63;
        const int w = tid >> 6;
        const int r16 = lane & 15;
        const int g = lane >> 4;
        const int row0 = bid * 128;
        const int row = row0 + w * 16 + r16;
        const int rowc = row < N_NODES ? row : N_NODES - 1;
        const float* xp = x + (size_t)rowc * D;
        f16x8 a[4];
#pragma unroll
        for (int kt = 0; kt < 4; ++kt) {
            const float4 lo = *(const float4*)(xp + kt * 32 + g * 8);
            const float4 hi = *(const float4*)(xp + kt * 32 + g * 8 + 4);
            f16x8 v;
            v[0] = (_Float16)lo.x; v[1] = (_Float16)lo.y; v[2] = (_Float16)lo.z; v[3] = (_Float16)lo.w;
            v[4] = (_Float16)hi.x; v[5] = (_Float16)hi.y; v[6] = (_Float16)hi.z; v[7] = (_Float16)hi.w;
            a[kt] = v;
        }
        {
            const int n = tid & 127;
            const int k0 = (tid >> 7) * 32;
#pragma unroll
            for (int c = 0; c < 4; ++c) {
                f16x8 v;
#pragma unroll
                for (int j = 0; j < 8; ++j) v[j] = (_Float16)W[(k0 + c * 8 + j) * D + n];
                const int byte = n * 256 + (k0 + c * 8) * 2;
                *(f16x8*)(smem + SWZ(byte)) = v;
            }
        }
        __syncthreads();
        f32x4 acc[8];
#pragma unroll
        for (int nt = 0; nt < 8; ++nt) {
            f32x4 c = {0.f, 0.f, 0.f, 0.f};
#pragma unroll
            for (int kt = 0; kt < 4; ++kt) {
                const int byte = (nt * 16 + r16) * 256 + kt * 64 + g * 16;
                const f16x8 b = *(const f16x8*)(smem + SWZ(byte));
                c = __builtin_amdgcn_mfma_f32_16x16x32_f16(a[kt], b, c, 0, 0, 0);
            }
            acc[nt] = c;
        }
        __syncthreads();
        _Float16* qs = (_Float16*)smem;  // D mapping (m89): D[(lane>>4)*4+r][lane&15]
#pragma unroll
        for (int nt = 0; nt < 8; ++nt)
#pragma unroll
            for (int r = 0; r < 4; ++r)
                qs[(w * 16 + g * 4 + r) * D + nt * 16 + r16] = (_Float16)acc[nt][r];
        __syncthreads();
        uint4* qg = (uint4*)q;
#pragma unroll
        for (int i = 0; i < 4; ++i) {
            const int c16 = tid + i * 512;
            const int grow = row0 + (c16 >> 4);
            if (grow < N_NODES)
                qg[(size_t)grow * 16 + (c16 & 15)] = *(const uint4*)(smem + c16 * 16);
        }
    } else {
        // ---- binA' path ----
        int* hist = (int*)smem;
        if (tid < NBKT) hist[tid] = 0;
        __syncthreads();
        const int i4 = (bid - NB_GEMM) * 512 + tid;
        const bool valid = i4 < N_EDGES / 4;
        int4 dv, sv;
        int lb0 = 0, lb1 = 0, lb2 = 0, lb3 = 0, lr0 = 0, lr1 = 0, lr2 = 0, lr3 = 0;
        if (valid) {
            dv = ((const int4*)dst)[i4];
            sv = ((const int4*)src)[i4];
            // per-node degree (L2-resident 400 KB): replaces binB's dinv
            atomicAdd(&cnt[dv.x], 1);
            atomicAdd(&cnt[dv.y], 1);
            atomicAdd(&cnt[dv.z], 1);
            atomicAdd(&cnt[dv.w], 1);
            lb0 = dv.x >> 8; lr0 = atomicAdd(&hist[lb0], 1);
            lb1 = dv.y >> 8; lr1 = atomicAdd(&hist[lb1], 1);
            lb2 = dv.z >> 8; lr2 = atomicAdd(&hist[lb2], 1);
            lb3 = dv.w >> 8; lr3 = atomicAdd(&hist[lb3], 1);
        }
        __syncthreads();
        if (tid < NBKT) {
            const int c = hist[tid];
            hist[tid] = c ? atomicAdd(&gcnt[tid], c) : 0;
        }
        __syncthreads();
        if (valid) {
            staged[lb0 * BKT_CAP + hist[lb0] + lr0] = (sv.x << 8) | (dv.x & 255);
            staged[lb1 * BKT_CAP + hist[lb1] + lr1] = (sv.y << 8) | (dv.y & 255);
            staged[lb2 * BKT_CAP + hist[lb2] + lr2] = (sv.z << 8) | (dv.z & 255);
            staged[lb3 * BKT_CAP + hist[lb3] + lr3] = (sv.w << 8) | (dv.w & 255);
        }
    }
}

// ==================== gatherB: quarter-bucket LDS-CSR + 16-lane/node gather ====================
// Grid = NBKT*4. Block (bucket, quarter) owns nodes [bucket*256+quarter*64, +64).
// CSR lives in LDS (no global esrc/row_ptr). Gather phase identical to the
// validated 65-us gather1: 16 lanes/node, 16B q-row loads, register acc,
// fused relu+W2 epilogue; plain y4 stores (each node owned by one block).

__global__ __launch_bounds__(256) void gatherB_kernel(const int* __restrict__ gcnt,
                                                      const int* __restrict__ staged,
                                                      const int* __restrict__ cnt,
                                                      const _Float16* __restrict__ q,
                                                      const float* __restrict__ b1,
                                                      const float* __restrict__ W2,
                                                      float* __restrict__ y4) {
    __shared__ int hist[64];
    __shared__ int scn[64];
    __shared__ int rpl[65];
    __shared__ int cur[64];
    __shared__ int esrc_lds[QCAP];
    const int t = threadIdx.x;
    const int bucket = blockIdx.x >> 2;
    const int quarter = blockIdx.x & 3;
    const int m = gcnt[bucket];
    const int* reg = staged + (size_t)bucket * BKT_CAP;
    if (t < 64) hist[t] = 0;
    __syncthreads();
    // pass 1: degree histogram for this quarter's 64 nodes
    for (int i = t; i < m; i += 256) {
        const int dl = reg[i] & 255;
        if ((dl >> 6) == quarter) atomicAdd(&hist[dl & 63], 1);
    }
    __syncthreads();
    // exclusive scan of hist -> rpl[0..64]
    if (t < 64) scn[t] = hist[t];
    __syncthreads();
    for (int off = 1; off < 64; off <<= 1) {
        const int u = (t < 64 && t >= off) ? scn[t - off] : 0;
        __syncthreads();
        if (t < 64) scn[t] += u;
        __syncthreads();
    }
    if (t < 64) { rpl[t + 1] = scn[t]; cur[t] = 0; }
    if (t == 0) rpl[0] = 0;
    __syncthreads();
    // pass 2: place srcs into the LDS edge list
    for (int i = t; i < m; i += 256) {
        const int rec = reg[i];
        const int dl = rec & 255;
        if ((dl >> 6) == quarter) {
            const int nl = dl & 63;
            const int pos = rpl[nl] + atomicAdd(&cur[nl], 1);
            esrc_lds[pos] = rec >> 8;
        }
    }
    __syncthreads();
    // gather: 4 rounds x 16 concurrent nodes x 16 lanes
    const int g = t & 15;
    union U { uint4 u; __half2 h2[4]; };
    const uint4* q4 = (const uint4*)q;
#pragma unroll
    for (int r = 0; r < 4; ++r) {
        const int nl = r * 16 + (t >> 4);
        const int node = bucket * 256 + quarter * 64 + nl;
        if (node >= N_NODES) continue;  // whole 16-lane group skips together
        const int beg = rpl[nl], end = rpl[nl + 1];
        float acc[8] = {0, 0, 0, 0, 0, 0, 0, 0};
        int j = beg;
        for (; j + 1 < end; j += 2) {  // two independent load chains
            const int s0 = esrc_lds[j];
            const int s1 = esrc_lds[j + 1];
            const float d0 = rsqrtf((float)cnt[s0] + 1.0f);
            const float d1 = rsqrtf((float)cnt[s1] + 1.0f);
            U u0, u1;
            u0.u = q4[(size_t)s0 * 16 + g];
            u1.u = q4[(size_t)s1 * 16 + g];
#pragma unroll
            for (int k = 0; k < 4; ++k) {
                const float2 f0 = __half22float2(u0.h2[k]);
                const float2 f1 = __half22float2(u1.h2[k]);
                acc[2 * k + 0] += f0.x * d0 + f1.x * d1;
                acc[2 * k + 1] += f0.y * d0 + f1.y * d1;
            }
        }
        if (j < end) {
            const int s = esrc_lds[j];
            const float ds = rsqrtf((float)cnt[s] + 1.0f);
            U u0; u0.u = q4[(size_t)s * 16 + g];
#pragma unroll
            for (int k = 0; k < 4; ++k) {
                const float2 f0 = __half22float2(u0.h2[k]);
                acc[2 * k + 0] += f0.x * ds;
                acc[2 * k + 1] += f0.y * ds;
            }
        }
        // self-loop + bias + relu
        const float dn = rsqrtf((float)cnt[node] + 1.0f);
        U un; un.u = q4[(size_t)node * 16 + g];
        const float4 ba = ((const float4*)b1)[g * 2];
        const float4 bb = ((const float4*)b1)[g * 2 + 1];
        float h[8];
#pragma unroll
        for (int k = 0; k < 4; ++k) {
            const float2 fn = __half22float2(un.h2[k]);
            h[2 * k + 0] = acc[2 * k + 0] + fn.x * dn;
            h[2 * k + 1] = acc[2 * k + 1] + fn.y * dn;
        }
        h[0] = fmaxf(h[0] * dn + ba.x, 0.f); h[1] = fmaxf(h[1] * dn + ba.y, 0.f);
        h[2] = fmaxf(h[2] * dn + ba.z, 0.f); h[3] = fmaxf(h[3] * dn + ba.w, 0.f);
        h[4] = fmaxf(h[4] * dn + bb.x, 0.f); h[5] = fmaxf(h[5] * dn + bb.y, 0.f);
        h[6] = fmaxf(h[6] * dn + bb.z, 0.f); h[7] = fmaxf(h[7] * dn + bb.w, 0.f);
        // fused gemm2 over channels c = 8g..8g+7
        const int c = g * 8;
        float a0 = 0.f, a1 = 0.f, a2 = 0.f;
#pragma unroll
        for (int k = 0; k < 8; ++k) {
            a0 += h[k] * W2[(c + k) * 3 + 0];
            a1 += h[k] * W2[(c + k) * 3 + 1];
            a2 += h[k] * W2[(c + k) * 3 + 2];
        }
#pragma unroll
        for (int off = 8; off; off >>= 1) {
            a0 += __shfl_xor(a0, off);
            a1 += __shfl_xor(a1, off);
            a2 += __shfl_xor(a2, off);
        }
        if (g == 0) {  // pre-scaled form y4[n] = xw2[n]*dinv[n] (R10 lesson)
            y4[(size_t)node * 4 + 0] = a0 * dn;
            y4[(size_t)node * 4 + 1] = a1 * dn;
            y4[(size_t)node * 4 + 2] = a2 * dn;
        }
    }
}

// ==================== scat2: layer-2 per-bucket aggregate (R12-validated) ====================

__global__ __launch_bounds__(256) void scat2_kernel(const int* __restrict__ gcnt,
                                                    const int* __restrict__ staged,
                                                    const int* __restrict__ cnt,
                                                    const float* __restrict__ y4,
                                                    const float* __restrict__ b2,
                                                    float* __restrict__ out) {
    __shared__ float a3[3][256];
    const int t = threadIdx.x;
    const int b = blockIdx.x;
    a3[0][t] = 0.f; a3[1][t] = 0.f; a3[2][t] = 0.f;
    __syncthreads();
    const int m = gcnt[b];
    const int* reg = staged + (size_t)b * BKT_CAP;
    for (int i = t; i < m; i += 256) {
        const int rec = reg[i];
        const int s = rec >> 8;
        const int dl = rec & 255;
        const float4 ys = *(const float4*)&y4[(size_t)s * 4];  // 1.6 MB, L2-resident
        atomicAdd(&a3[0][dl], ys.x);
        atomicAdd(&a3[1][dl], ys.y);
        atomicAdd(&a3[2][dl], ys.z);
    }
    __syncthreads();
    const int node = b * 256 + t;
    if (node < N_NODES) {
        const float dn = rsqrtf((float)cnt[node] + 1.0f);
        const float4 yn = *(const float4*)&y4[(size_t)node * 4];
        out[node * 3 + 0] = (a3[0][t] + yn.x) * dn + b2[0];
        out[node * 3 + 1] = (a3[1][t] + yn.y) * dn + b2[1];
        out[node * 3 + 2] = (a3[2][t] + yn.z) * dn + b2[2];
    }
}

// ==================== launch ====================

extern "C" void kernel_launch(void* const* d_in, const int* in_sizes, int n_in,
                              void* d_out, int out_size, void* d_ws, size_t ws_size,
                              hipStream_t stream) {
    const float* feature = (const float*)d_in[0];
    const int* edge_index = (const int*)d_in[1];
    const int* src = edge_index;             // edge_index[0, :]
    const int* dst = edge_index + N_EDGES;   // edge_index[1, :]
    const float* W1 = (const float*)d_in[3];
    const float* b1 = (const float*)d_in[4];
    const float* W2 = (const float*)d_in[5];
    const float* b2 = (const float*)d_in[6];
    float* out = (float*)d_out;

    const size_t ND = (size_t)N_NODES * D;
    _Float16* q   = (_Float16*)d_ws;                   // 25.6 MB fp16, q[node][128]
    float* y4     = (float*)(q + ND);                  // 1.6 MB (N*4, .w unused)
    int*   cnt    = (int*)(y4 + (size_t)N_NODES * 4);  // 0.4 MB per-node degree
    int*   gcnt   = cnt + N_NODES;                     // 1.6 KB (contiguous: one memset)
    int*   staged = gcnt + NBKT;                       // 8.0 MB

    hipMemsetAsync(cnt, 0, (N_NODES + NBKT) * sizeof(int), stream);
    mega_kernel<<<NB_GEMM + NB_BINA, 512, 0, stream>>>(feature, W1, q, src, dst, cnt, gcnt, staged);
    gatherB_kernel<<<NBKT * 4, 256, 0, stream>>>(gcnt, staged, cnt, q, b1, W2, y4);
    scat2_kernel<<<NBKT, 256, 0, stream>>>(gcnt, staged, cnt, y4, b2, out);
}